// Round 2
// baseline (775.508 us; speedup 1.0000x reference)
//
#include <hip/hip_runtime.h>

#define TSTEPS 512
#define PD 8  // prefetch depth (steps); 4 loads/step * 8 = 32 outstanding < 63 vmcnt limit

typedef __bf16 bf16x8 __attribute__((ext_vector_type(8)));
typedef float f32x16 __attribute__((ext_vector_type(16)));
typedef unsigned int uint4v __attribute__((ext_vector_type(4)));

// float -> bf16 round-to-nearest-even, bit trick (explicit, no libcall)
__device__ __forceinline__ unsigned f2bf(float f) {
    unsigned u = __float_as_uint(f);
    return (u + 0x7fffu + ((u >> 16) & 1u)) >> 16;
}
__device__ __forceinline__ unsigned packbf(float lo, float hi) {
    return f2bf(lo) | (f2bf(hi) << 16);
}

// One wave per batch. Recurrence in transposed space: g = h^T,
//   g_{t+1} = (b + x_t)^T @ (b2^T + g_t)
// MFMA D=A*B: A = M^T (from x, via LDS gather), B = b2^T + g (pure registers).
// C/D layout (verified m74/m101): col = lane&31, row = (reg&3) + 8*(reg>>2) + 4*(lane>>5).
// K-slot permutation kappa(c,h,j) = c*16 + 4h + (j&3) + 8*(j>>2) makes the B fragment
// equal the natural C/D register order (call0 = regs 0..7, call1 = regs 8..15).
__global__ void __launch_bounds__(64, 1)
minrnn_kernel(const float* __restrict__ x, const float* __restrict__ bvec,
              const float* __restrict__ b2vec, const float* __restrict__ h0,
              float* __restrict__ out)
{
    __shared__ float4 xs4[256];           // one 4KB staging slot for x_t
    float* xs = (float*)xs4;

    const int l    = threadIdx.x;         // 0..63
    const int col  = l & 31;
    const int half = l >> 5;
    const int bb   = blockIdx.x;          // batch index

    // Preload per-lane constants: b2^T in C/D layout, initial g from h0, b in A-frag (kappa) order.
    float b2T[16], g[16], bA[16];
#pragma unroll
    for (int i = 0; i < 16; ++i) {
        const int row = (i & 3) + 8 * (i >> 2) + 4 * half;
        b2T[i] = b2vec[col * 32 + row];        // b2^T[row][col] = b2[col*32+row]
        g[i]   = h0[bb * 1024 + col * 32 + row]; // g = h0^T (zeros, but be exact)
    }
#pragma unroll
    for (int c = 0; c < 2; ++c)
#pragma unroll
        for (int j = 0; j < 8; ++j) {
            const int k = c * 16 + half * 4 + (j & 3) + 8 * (j >> 2); // kappa
            bA[c * 8 + j] = bvec[k * 32 + col];   // A[m=col][k] bias = b[k*32+col]
        }

    const float4* xb = (const float4*)(x + (size_t)bb * TSTEPS * 1024);

    // Register ring: deep prefetch to cover ~900cyc HBM latency at ~20 B/cyc/CU.
    float4 ring[PD][4];
#pragma unroll
    for (int d = 0; d < PD; ++d)
#pragma unroll
        for (int q = 0; q < 4; ++q)
            ring[d][q] = xb[d * 256 + q * 64 + l];

    const f32x16 zero = {0.f,0.f,0.f,0.f,0.f,0.f,0.f,0.f,
                         0.f,0.f,0.f,0.f,0.f,0.f,0.f,0.f};

    for (int tt = 0; tt < TSTEPS / PD; ++tt) {
#pragma unroll
        for (int p = 0; p < PD; ++p) {
            const int t = tt * PD + p;

            // Stage x_t (arrived PD steps ago) into LDS. Single wave: DS pipe is
            // in-order per wave, no barrier needed anywhere.
#pragma unroll
            for (int q = 0; q < 4; ++q)
                xs4[q * 64 + l] = ring[p][q];

            // Prefetch x_{t+PD} into the freed ring slot (clamped; uniform branch-free).
            {
                int tp = t + PD; if (tp > TSTEPS - 1) tp = TSTEPS - 1;
#pragma unroll
                for (int q = 0; q < 4; ++q)
                    ring[p][q] = xb[tp * 256 + q * 64 + l];
            }

            // B operand: (g + b2^T) in natural register order == kappa frag order.
            unsigned pb[8];
#pragma unroll
            for (int i = 0; i < 8; ++i)
                pb[i] = packbf(g[2*i] + b2T[2*i], g[2*i+1] + b2T[2*i+1]);
            const bf16x8 B0 = __builtin_bit_cast(bf16x8, (uint4v){pb[0], pb[1], pb[2], pb[3]});
            const bf16x8 B1 = __builtin_bit_cast(bf16x8, (uint4v){pb[4], pb[5], pb[6], pb[7]});

            // A operand: gather (b + x_t) from LDS in kappa order.
            // float index = kappa*32 + col = c*512 + half*128 + (j>>2)*256 + (j&3)*32 + col
            // bank = col (two halves alias 2-way -> free).
            float xg[16];
#pragma unroll
            for (int c = 0; c < 2; ++c)
#pragma unroll
                for (int j = 0; j < 8; ++j)
                    xg[c*8+j] = xs[c*512 + half*128 + (j>>2)*256 + (j&3)*32 + col]
                                + bA[c*8+j];
            unsigned pa[8];
#pragma unroll
            for (int i = 0; i < 8; ++i)
                pa[i] = packbf(xg[2*i], xg[2*i+1]);
            const bf16x8 A0 = __builtin_bit_cast(bf16x8, (uint4v){pa[0], pa[1], pa[2], pa[3]});
            const bf16x8 A1 = __builtin_bit_cast(bf16x8, (uint4v){pa[4], pa[5], pa[6], pa[7]});

            // g_{t+1} = A*B, fp32 accumulate, chained over the two K-halves.
            f32x16 acc = __builtin_amdgcn_mfma_f32_32x32x16_bf16(A0, B0, zero, 0, 0, 0);
            acc        = __builtin_amdgcn_mfma_f32_32x32x16_bf16(A1, B1, acc,  0, 0, 0);
#pragma unroll
            for (int i = 0; i < 16; ++i) g[i] = acc[i];
        }
    }

    // out = h_T = g^T : lane holds g[row][col] -> out[col*32 + row]
#pragma unroll
    for (int i = 0; i < 16; ++i) {
        const int row = (i & 3) + 8 * (i >> 2) + 4 * half;
        out[bb * 1024 + col * 32 + row] = g[i];
    }
}

extern "C" void kernel_launch(void* const* d_in, const int* in_sizes, int n_in,
                              void* d_out, int out_size, void* d_ws, size_t ws_size,
                              hipStream_t stream)
{
    const float* x  = (const float*)d_in[0];
    const float* b  = (const float*)d_in[1];
    const float* b2 = (const float*)d_in[2];
    const float* h0 = (const float*)d_in[3];
    float* out = (float*)d_out;
    minrnn_kernel<<<128, 64, 0, stream>>>(x, b, b2, h0, out);
}

// Round 3
// 541.724 us; speedup vs baseline: 1.4316x; 1.4316x over previous
//
#include <hip/hip_runtime.h>

#define TSTEPS 512
#define NP 7            // producer waves per block
#define S  32           // ring slots (power of 2)

typedef __bf16 bf16x8 __attribute__((ext_vector_type(8)));
typedef float f32x16 __attribute__((ext_vector_type(16)));
typedef unsigned int uint4v __attribute__((ext_vector_type(4)));

// float -> bf16 round-to-nearest-even
__device__ __forceinline__ unsigned f2bf(float f) {
    unsigned u = __float_as_uint(f);
    return (u + 0x7fffu + ((u >> 16) & 1u)) >> 16;
}
__device__ __forceinline__ unsigned packbf(float lo, float hi) {
    return f2bf(lo) | (f2bf(hi) << 16);
}

// One block per batch. Wave 0 = consumer (the sequential recurrence, MFMA).
// Waves 1..7 = producers: x_t -> kappa-gathered, bias-added, bf16-packed
// A-fragments in a 32-slot LDS ring. Latency hiding comes from wave
// parallelism (robust), not compiler scheduling (round-2 failure: RA sank
// the register-ring prefetch loads, VGPR_Count=64 proved ring never existed).
//
// Recurrence in transposed space: g = h^T,  g_{t+1} = (b+x_t)^T @ (b2^T + g_t)
// C/D layout: col=lane&31, row=(reg&3)+8*(reg>>2)+4*(lane>>5)  [verified R0/R2:
// absmax 2.44e-4 pass]. kappa(c,h,j)=c*16+4h+(j&3)+8*(j>>2) makes the B
// fragment equal the natural C/D register order -> recurrent state never
// crosses lanes.
__global__ void __launch_bounds__(64 * (NP + 1))
minrnn_kernel(const float* __restrict__ x, const float* __restrict__ bvec,
              const float* __restrict__ b2vec, const float* __restrict__ h0,
              float* __restrict__ out)
{
    __shared__ unsigned ring[S * 512];       // 64 KB: packed bf16 A-frags, slot[d*64+lane]
    __shared__ float    scratch[NP * 1024];  // 28 KB: raw x_t staging, per producer
    __shared__ int      flags[S];            // slot t published iff flags[t%S] == t+1
    __shared__ int      consumed;            // consumer has finished reading slot <= consumed

    const int tid  = threadIdx.x;
    const int wave = tid >> 6;
    const int l    = tid & 63;
    const int col  = l & 31;
    const int half = l >> 5;
    const int bb   = blockIdx.x;

    if (tid < S) flags[tid] = 0;
    if (tid == 0) consumed = -1;
    __syncthreads();

    volatile int* vflags = flags;
    volatile int* vcons  = &consumed;

    if (wave == 0) {
        // ---------------- consumer ----------------
        float b2T[16], g[16];
#pragma unroll
        for (int i = 0; i < 16; ++i) {
            const int row = (i & 3) + 8 * (i >> 2) + 4 * half;
            b2T[i] = b2vec[col * 32 + row];
            g[i]   = h0[bb * 1024 + col * 32 + row];
        }
        volatile unsigned* vring = ring;

        // prologue: wait for slot 0, read it, prefetch flag for slot 1
        while (vflags[0] != 1) {}
        unsigned cur[8], nxt[8];
#pragma unroll
        for (int d = 0; d < 8; ++d) cur[d] = vring[d * 64 + l];
        int flagn = vflags[1];

        const f32x16 zero = {0.f,0.f,0.f,0.f,0.f,0.f,0.f,0.f,
                             0.f,0.f,0.f,0.f,0.f,0.f,0.f,0.f};

        for (int t = 0; t < TSTEPS; ++t) {
            if (t < TSTEPS - 1) {
                const int tn = t + 1;
                // verify (usually prefetched) flag; spin only if producer behind
                while (flagn != tn + 1) flagn = vflags[tn & (S - 1)];
                const int sb = (tn & (S - 1)) << 9;
#pragma unroll
                for (int d = 0; d < 8; ++d) nxt[d] = vring[sb + d * 64 + l];
                if (tn < TSTEPS - 1) flagn = vflags[(tn + 1) & (S - 1)];
            }
            if (l == 0) *vcons = t - 2;   // lagged publish: keeps >=2-slot guard

            // B operand: (g + b2^T) in natural register order == kappa frag order
            unsigned pb[8];
#pragma unroll
            for (int i = 0; i < 8; ++i)
                pb[i] = packbf(g[2*i] + b2T[2*i], g[2*i+1] + b2T[2*i+1]);
            const bf16x8 B0 = __builtin_bit_cast(bf16x8, (uint4v){pb[0], pb[1], pb[2], pb[3]});
            const bf16x8 B1 = __builtin_bit_cast(bf16x8, (uint4v){pb[4], pb[5], pb[6], pb[7]});
            const bf16x8 A0 = __builtin_bit_cast(bf16x8, (uint4v){cur[0], cur[1], cur[2], cur[3]});
            const bf16x8 A1 = __builtin_bit_cast(bf16x8, (uint4v){cur[4], cur[5], cur[6], cur[7]});

            f32x16 acc = __builtin_amdgcn_mfma_f32_32x32x16_bf16(A0, B0, zero, 0, 0, 0);
            acc        = __builtin_amdgcn_mfma_f32_32x32x16_bf16(A1, B1, acc,  0, 0, 0);
#pragma unroll
            for (int i = 0; i < 16; ++i) g[i] = acc[i];
#pragma unroll
            for (int d = 0; d < 8; ++d) cur[d] = nxt[d];
        }

        // out = g^T : lane holds g[row][col] -> out[col*32 + row]
#pragma unroll
        for (int i = 0; i < 16; ++i) {
            const int row = (i & 3) + 8 * (i >> 2) + 4 * half;
            out[bb * 1024 + col * 32 + row] = g[i];
        }
    } else {
        // ---------------- producers ----------------
        const int p = wave - 1;
        float bA[16];
#pragma unroll
        for (int c = 0; c < 2; ++c)
#pragma unroll
            for (int j = 0; j < 8; ++j) {
                const int k = c * 16 + half * 4 + (j & 3) + 8 * (j >> 2); // kappa
                bA[c * 8 + j] = bvec[k * 32 + col];
            }
        float* myscr = scratch + p * 1024;
        const float4* xb = (const float4*)(x + (size_t)bb * TSTEPS * 1024);

        for (int t = p; t < TSTEPS; t += NP) {
            // coalesced load of x_t (4 KB per wave: 4 x dwordx4)
            float4 v[4];
#pragma unroll
            for (int q = 0; q < 4; ++q) v[q] = xb[t * 256 + q * 64 + l];

            // wait for ring space (consumer must have consumed slot t-S)
            while (*vcons < t - S) {}

            // stage raw, then kappa-gather + bias + pack (all off critical path)
#pragma unroll
            for (int q = 0; q < 4; ++q) ((float4*)myscr)[q * 64 + l] = v[q];
            float xg[16];
#pragma unroll
            for (int c = 0; c < 2; ++c)
#pragma unroll
                for (int j = 0; j < 8; ++j)
                    xg[c*8+j] = myscr[c*512 + half*128 + (j>>2)*256 + (j&3)*32 + col]
                                + bA[c*8+j];
            unsigned pa[8];
#pragma unroll
            for (int i = 0; i < 8; ++i)
                pa[i] = packbf(xg[2*i], xg[2*i+1]);

            const int sb = (t & (S - 1)) << 9;
#pragma unroll
            for (int d = 0; d < 8; ++d) ring[sb + d * 64 + l] = pa[d];

            __threadfence_block();            // data writes ordered before flag publish
            if (l == 0) vflags[t & (S - 1)] = t + 1;
        }
    }
}

extern "C" void kernel_launch(void* const* d_in, const int* in_sizes, int n_in,
                              void* d_out, int out_size, void* d_ws, size_t ws_size,
                              hipStream_t stream)
{
    const float* x  = (const float*)d_in[0];
    const float* b  = (const float*)d_in[1];
    const float* b2 = (const float*)d_in[2];
    const float* h0 = (const float*)d_in[3];
    float* out = (float*)d_out;
    minrnn_kernel<<<128, 64 * (NP + 1), 0, stream>>>(x, b, b2, h0, out);
}

// Round 4
// 364.799 us; speedup vs baseline: 2.1258x; 1.4850x over previous
//
#include <hip/hip_runtime.h>

#define TSTEPS 512
#define NP 7            // producer waves per block
#define S  32           // ring slots (power of 2)

typedef __bf16 bf16x8 __attribute__((ext_vector_type(8)));
typedef float f32x16 __attribute__((ext_vector_type(16)));
typedef unsigned int uint4v __attribute__((ext_vector_type(4)));

// ---- bf16 pack (RNE). gfx950 has v_cvt_pk_bf16_f32; guarded fallback uses
// the add-round + v_perm_b32 byte-select trick (7 insts vs 1).
#if __has_builtin(__builtin_amdgcn_cvt_pk_bf16_f32)
__device__ __forceinline__ unsigned packbf(float lo, float hi) {
    return __builtin_bit_cast(unsigned, __builtin_amdgcn_cvt_pk_bf16_f32(lo, hi));
}
#else
__device__ __forceinline__ unsigned rne_(float f) {
    unsigned u = __float_as_uint(f);
    return u + 0x7fffu + ((u >> 16) & 1u);
}
__device__ __forceinline__ unsigned packbf(float lo, float hi) {
    // result bytes: [lo.b2, lo.b3, hi.b2, hi.b3]
    return __builtin_amdgcn_perm(rne_(hi), rne_(lo), 0x07060302u);
}
#endif

__device__ __forceinline__ int ldf(const int* p) {
    return __hip_atomic_load(p, __ATOMIC_RELAXED, __HIP_MEMORY_SCOPE_WORKGROUP);
}
__device__ __forceinline__ void stf(int* p, int v) {
    __hip_atomic_store(p, v, __ATOMIC_RELAXED, __HIP_MEMORY_SCOPE_WORKGROUP);
}

// One block per batch (128 blocks). Wave 0 = consumer: the sequential
// recurrence entirely in MFMA C/D register space. Waves 1..7 = producers:
// load x_t from global in kappa-gather order (per (c,j): two contiguous 128B
// segments -> coalesced), add b, pack bf16, deposit A-frags in a 32-slot ring.
//
// Recurrence (transposed space, u = h^T + b2^T):
//   u_{t+1} = (b+x_t)^T @ bf16(u_t) + b2^T   via MFMA C-operand = b2^T.
// C/D layout: col=lane&31, row=(reg&3)+8*(reg>>2)+4*(lane>>5).
// kappa(c,h,j)=c*16+4h+(j&3)+8*(j>>2) makes the B fragment equal the natural
// C/D register order -> recurrent state never crosses lanes.
// [Layout + numerics verified R2/R3: absmax 2.44e-4.]
//
// Sync: flags[s] == t+1 publishes slot t (exact sequence values, no ABA);
// relaxed atomics + __threadfence_block() for order; ring reads/writes are
// PLAIN accesses so they vectorize/pipeline (round-3 lesson: volatile ring
// reads serialized 8 ds_reads -> ~1100 cyc/step).
__global__ void __launch_bounds__(64 * (NP + 1), 1)
minrnn_kernel(const float* __restrict__ x, const float* __restrict__ bvec,
              const float* __restrict__ b2vec, const float* __restrict__ h0,
              float* __restrict__ out)
{
    __shared__ unsigned ring[S * 512];   // 64 KB, slot base (t%S)*512, elem d*64+l
    __shared__ int flags[S];
    __shared__ int consumed;             // iterations <= consumed fully done

    const int tid  = threadIdx.x;
    const int wave = tid >> 6;
    const int l    = tid & 63;
    const int col  = l & 31;
    const int half = l >> 5;
    const int bb   = blockIdx.x;

    if (tid < S) flags[tid] = 0;
    if (tid == 0) consumed = -1;
    __syncthreads();

    if (wave == 0) {
        // ---------------- consumer ----------------
        float u[16];
        f32x16 cb2;
#pragma unroll
        for (int i = 0; i < 16; ++i) {
            const int row = (i & 3) + 8 * (i >> 2) + 4 * half;
            const float b2v = b2vec[col * 32 + row];
            cb2[i] = b2v;
            u[i] = h0[bb * 1024 + col * 32 + row] + b2v;
        }

        // prologue: wait slot 0, read into cur, prefetch flag 1
        int flagn = ldf(&flags[0]);
        while (flagn != 1) flagn = ldf(&flags[0]);
        __threadfence_block();
        unsigned cur[8], nxt[8];
#pragma unroll
        for (int d = 0; d < 8; ++d) cur[d] = ring[d * 64 + l];
        flagn = ldf(&flags[1]);

        for (int t = 0; t < TSTEPS; ++t) {
            if (t < TSTEPS - 1) {
                const int want = t + 2;           // flag value for slot t+1
                while (flagn != want) flagn = ldf(&flags[(t + 1) & (S - 1)]);
                __threadfence_block();            // acquire: order ring reads after flag
                const int sb = ((t + 1) & (S - 1)) << 9;
#pragma unroll
                for (int d = 0; d < 8; ++d) nxt[d] = ring[sb + d * 64 + l];
                if (t + 2 < TSTEPS) flagn = ldf(&flags[(t + 2) & (S - 1)]);
            }

            // B operand: bf16(u) in natural register order == kappa frag order
            unsigned pb[8];
#pragma unroll
            for (int i = 0; i < 8; ++i) pb[i] = packbf(u[2 * i], u[2 * i + 1]);
            const bf16x8 B0 = __builtin_bit_cast(bf16x8, (uint4v){pb[0], pb[1], pb[2], pb[3]});
            const bf16x8 B1 = __builtin_bit_cast(bf16x8, (uint4v){pb[4], pb[5], pb[6], pb[7]});
            const bf16x8 A0 = __builtin_bit_cast(bf16x8, (uint4v){cur[0], cur[1], cur[2], cur[3]});
            const bf16x8 A1 = __builtin_bit_cast(bf16x8, (uint4v){cur[4], cur[5], cur[6], cur[7]});

            f32x16 acc = __builtin_amdgcn_mfma_f32_32x32x16_bf16(A0, B0, cb2, 0, 0, 0);
            acc        = __builtin_amdgcn_mfma_f32_32x32x16_bf16(A1, B1, acc, 0, 0, 0);
#pragma unroll
            for (int i = 0; i < 16; ++i) u[i] = acc[i];

            if (l == 0 && (t & 7) == 7) stf(&consumed, t);
#pragma unroll
            for (int d = 0; d < 8; ++d) cur[d] = nxt[d];
        }

        // out = u - b2^T = g^T : lane holds g[row][col] -> out[col*32+row]
#pragma unroll
        for (int i = 0; i < 16; ++i) {
            const int row = (i & 3) + 8 * (i >> 2) + 4 * half;
            out[bb * 1024 + col * 32 + row] = u[i] - cb2[i];
        }
    } else {
        // ---------------- producers ----------------
        const int p = wave - 1;
        float bA[16];
        int off[16];
#pragma unroll
        for (int c = 0; c < 2; ++c)
#pragma unroll
            for (int j = 0; j < 8; ++j) {
                const int k = c * 16 + half * 4 + (j & 3) + 8 * (j >> 2); // kappa
                bA[c * 8 + j] = bvec[k * 32 + col];
                off[c * 8 + j] = c * 512 + half * 128 + (j >> 2) * 256 + (j & 3) * 32 + col;
            }
        const float* xb = x + (size_t)bb * TSTEPS * 1024;

        auto emit = [&](int t, const float* v) {
            // ring space + flag-slot reuse guard (see sequence-number analysis)
            while (ldf(&consumed) < t - 33) {}
            unsigned pa[8];
#pragma unroll
            for (int i = 0; i < 8; ++i)
                pa[i] = packbf(v[2 * i] + bA[2 * i], v[2 * i + 1] + bA[2 * i + 1]);
            const int sb = (t & (S - 1)) << 9;
#pragma unroll
            for (int d = 0; d < 8; ++d) ring[sb + d * 64 + l] = pa[d];
            __threadfence_block();               // release: data before flag
            if (l == 0) stf(&flags[t & (S - 1)], t + 1);
        };

        // 2-batch software pipeline; sched_barrier pins load issue (round-2:
        // RA sank prefetch loads to use site, killing the pipeline).
        for (int t = p; t < TSTEPS; t += 2 * NP) {
            const int t2 = t + NP;
            float va[16], vb[16];
#pragma unroll
            for (int i = 0; i < 16; ++i) va[i] = xb[t * 1024 + off[i]];
            if (t2 < TSTEPS) {
#pragma unroll
                for (int i = 0; i < 16; ++i) vb[i] = xb[t2 * 1024 + off[i]];
            }
            __builtin_amdgcn_sched_barrier(0);
            emit(t, va);
            if (t2 < TSTEPS) emit(t2, vb);
        }
    }
}

extern "C" void kernel_launch(void* const* d_in, const int* in_sizes, int n_in,
                              void* d_out, int out_size, void* d_ws, size_t ws_size,
                              hipStream_t stream)
{
    const float* x  = (const float*)d_in[0];
    const float* b  = (const float*)d_in[1];
    const float* b2 = (const float*)d_in[2];
    const float* h0 = (const float*)d_in[3];
    float* out = (float*)d_out;
    minrnn_kernel<<<128, 64 * (NP + 1), 0, stream>>>(x, b, b2, h0, out);
}